// Round 1
// 231.112 us; speedup vs baseline: 1.0212x; 1.0212x over previous
//
#include <hip/hip_runtime.h>
#include <cstdint>

#define NEG_SLOPE 0.2f

__device__ __forceinline__ float leaky(float v) { return v > 0.f ? v : NEG_SLOPE * v; }
__device__ __forceinline__ float elu(float v) { return v > 0.f ? v : __expf(v) - 1.f; }

typedef _Float16 half2v __attribute__((ext_vector_type(2)));
typedef _Float16 f16x8 __attribute__((ext_vector_type(8)));
typedef float f32x4 __attribute__((ext_vector_type(4)));
union H8 { float4 f4; half2v h[4]; };   // 16 B = 8 halves
union H4 { float2 f2; half2v h[2]; };   // 8 B = 4 halves
union HF2 { float2 f2; _Float16 h[4]; };

// ---------------- prep: zero counts + fp16-transpose weights ----------------
// W1t[c][k] = (fp16) W1[k][c]  (128x128); W2t[c][k] = (fp16) W2[k][c] (32x128)

__global__ __launch_bounds__(256) void prep_kernel(const float* __restrict__ W1,
                                                   const float* __restrict__ W2,
                                                   _Float16* __restrict__ W1t,
                                                   _Float16* __restrict__ W2t,
                                                   int* __restrict__ cnt, int n) {
    int i = blockIdx.x * 256 + threadIdx.x;
    if (i < n) cnt[i] = 0;
    if (i < 128 * 128) { int c = i >> 7, k = i & 127; W1t[i] = (_Float16)W1[k * 128 + c]; }
    if (i < 32 * 128)  { int c = i >> 7, k = i & 127; W2t[i] = (_Float16)W2[k * 32 + c]; }
}

// ---------------- parallel scan, 2 dispatches ----------------

__global__ __launch_bounds__(256) void scanA_kernel(const int* __restrict__ cnt,
                                                    int* __restrict__ bsum, int n) {
    int base = blockIdx.x * 1024 + threadIdx.x * 4;
    int s = 0;
    if (base + 3 < n) {
        int4 v = *(const int4*)(cnt + base);
        s = v.x + v.y + v.z + v.w;
    } else {
        for (int j = 0; j < 4; ++j) if (base + j < n) s += cnt[base + j];
    }
#pragma unroll
    for (int o = 1; o < 64; o <<= 1) s += __shfl_xor(s, o);
    __shared__ int ws_[4];
    if ((threadIdx.x & 63) == 0) ws_[threadIdx.x >> 6] = s;
    __syncthreads();
    if (threadIdx.x == 0) bsum[blockIdx.x] = ws_[0] + ws_[1] + ws_[2] + ws_[3];
}

// G <= 64 assumed (N <= 65536).
__global__ __launch_bounds__(256) void scanC_kernel(const int* __restrict__ cnt,
                                                    const int* __restrict__ bsum,
                                                    int* __restrict__ rp, int n, int G) {
    __shared__ int bpre[64];            // exclusive prefix of block sums
    int b = blockIdx.x, t = threadIdx.x;
    if (t < 64) {
        int lane = t;
        int v = (lane < G) ? bsum[lane] : 0;
        int x = v;
#pragma unroll
        for (int o = 1; o < 64; o <<= 1) { int u = __shfl_up(x, o); if (lane >= o) x += u; }
        bpre[lane] = x - v;             // exclusive
    }
    __syncthreads();
    int base = b * 1024 + t * 4;
    int v[4]; int s = 0;
#pragma unroll
    for (int j = 0; j < 4; ++j) { int idx = base + j; v[j] = (idx < n) ? cnt[idx] : 0; s += v[j]; }
    int lane = t & 63;
    int x = s;
#pragma unroll
    for (int o = 1; o < 64; o <<= 1) { int u = __shfl_up(x, o); if (lane >= o) x += u; }
    __shared__ int wsum[4], woff[4];
    if (lane == 63) wsum[t >> 6] = x;
    __syncthreads();
    if (t == 0) { int a = 0; for (int i = 0; i < 4; ++i) { woff[i] = a; a += wsum[i]; } }
    __syncthreads();
    int off = bpre[b] + (x - s) + woff[t >> 6];
#pragma unroll
    for (int j = 0; j < 4; ++j) {
        int idx = base + j;
        if (idx <= n) rp[idx] = off;
        off += v[j];
    }
}

// ---------------- scatter (rank-based, atomic-free) ----------------

__global__ void scatter_kernel(const int* __restrict__ src, const int* __restrict__ dstp,
                               const int* __restrict__ rp, const int* __restrict__ ranks,
                               int* __restrict__ col, int E) {
    int i = blockIdx.x * blockDim.x + threadIdx.x;
    if (i < E) col[rp[dstp[i]] + ranks[i]] = src[i];
}

// ---------------- GEMM1 (MFMA fp16) + fused edge count ----------------
// Block tile: 64 rows x 128 cols, 4 waves (wave w owns rows w*16..w*16+15).
// mfma_f32_16x16x32_f16: A lane(row=l&15, k=(l>>4)*8+j); B lane(col=l&15, same k);
// D lane(col=l&15, row=(l>>4)*4+reg).   LDS rows padded to 136 halves.

#define LDA 136

__global__ __launch_bounds__(256) void gemm1_count_kernel(
        const float* __restrict__ x, const _Float16* __restrict__ W1t,
        const float* __restrict__ a_src, const float* __restrict__ a_dst,
        _Float16* __restrict__ h1h, float* __restrict__ as1, float* __restrict__ ad1,
        int n, int gemmBlocks,
        const int* __restrict__ dstp, int* __restrict__ cnt, int* __restrict__ ranks, int E) {
    if ((int)blockIdx.x >= gemmBlocks) {
        int i = ((int)blockIdx.x - gemmBlocks) * 256 + threadIdx.x;
        if (i < E) ranks[i] = atomicAdd(&cnt[dstp[i]], 1);
        return;
    }
    __shared__ _Float16 Ah[64 * LDA];    // x tile fp16, also reused as epilogue buffer
    __shared__ _Float16 Bh[128 * LDA];   // W1t tile fp16
    int tid = threadIdx.x;
    int row0 = (int)blockIdx.x * 64;

    // stage x tile (fp32 -> fp16), 8 B LDS writes, conflict-free
    const float4* x4 = (const float4*)x;
#pragma unroll
    for (int i = 0; i < 8; ++i) {
        int idx = tid + i * 256;          // float4 id: row*32 + c4
        int row = idx >> 5, c4 = idx & 31;
        float4 v = make_float4(0.f, 0.f, 0.f, 0.f);
        if (row0 + row < n) v = x4[(size_t)(row0 + row) * 32 + c4];
        HF2 u;
        u.h[0] = (_Float16)v.x; u.h[1] = (_Float16)v.y;
        u.h[2] = (_Float16)v.z; u.h[3] = (_Float16)v.w;
        *(float2*)&Ah[row * LDA + c4 * 4] = u.f2;
    }
    // stage W1t (already fp16): 128 rows x 16 float4, pad stride = 17 float4
    const float4* Ws = (const float4*)W1t;
    float4* Bd = (float4*)Bh;
#pragma unroll
    for (int i = 0; i < 8; ++i) {
        int idx = tid + i * 256;
        int r = idx >> 4, j = idx & 15;
        Bd[r * 17 + j] = Ws[idx];
    }
    __syncthreads();

    int l = tid & 63, w = tid >> 6;
    int lr = l & 15, lg = l >> 4;
    f16x8 af[4];
#pragma unroll
    for (int kk = 0; kk < 4; ++kk)
        af[kk] = *(const f16x8*)&Ah[(w * 16 + lr) * LDA + kk * 32 + lg * 8];
    f32x4 acc[8];
#pragma unroll
    for (int t = 0; t < 8; ++t) acc[t] = (f32x4)0.f;
#pragma unroll
    for (int t = 0; t < 8; ++t) {
#pragma unroll
        for (int kk = 0; kk < 4; ++kk) {
            f16x8 bf = *(const f16x8*)&Bh[(t * 16 + lr) * LDA + kk * 32 + lg * 8];
            acc[t] = __builtin_amdgcn_mfma_f32_16x16x32_f16(af[kk], bf, acc[t], 0, 0, 0);
        }
    }
    __syncthreads();
    // epilogue: fp16 acc -> LDS (transpose to row-contiguous), then vector stores
#pragma unroll
    for (int t = 0; t < 8; ++t)
#pragma unroll
        for (int r = 0; r < 4; ++r)
            Ah[(w * 16 + lg * 4 + r) * LDA + t * 16 + lr] = (_Float16)acc[t][r];
    __syncthreads();
    // thread = (row, head): 16B h1h stores + alpha dots with no cross-lane reduce
    int row = tid >> 2, q = tid & 3;
    if (row0 + row < n) {
        const float* asv = a_src + q * 32;
        const float* adv = a_dst + q * 32;
        float ps = 0.f, pd = 0.f;
#pragma unroll
        for (int j = 0; j < 4; ++j) {
            f16x8 v = *(const f16x8*)&Ah[row * LDA + q * 32 + j * 8];
            *(f16x8*)&h1h[(size_t)(row0 + row) * 128 + q * 32 + j * 8] = v;
#pragma unroll
            for (int e = 0; e < 8; ++e) {
                float f = (float)v[e];
                ps += f * asv[j * 8 + e];
                pd += f * adv[j * 8 + e];
            }
        }
        as1[(row0 + row) * 4 + q] = ps;
        ad1[(row0 + row) * 4 + q] = pd;
    }
}

// ---------------- GEMM2 (MFMA fp16, no LDS): h2 = hp @ W2 + fused alpha dots ----------------
// Block = 64 rows, 4 waves x 16 rows; 32 out cols = 2 col-tiles. A frags direct
// from global (fp16, 16 KB/block -> L1); W2t broadcast from L2.

__global__ __launch_bounds__(256) void gemm2_kernel(const _Float16* __restrict__ hph,
                                                    const _Float16* __restrict__ W2t,
                                                    const float* __restrict__ a_src,
                                                    const float* __restrict__ a_dst,
                                                    _Float16* __restrict__ h2h,
                                                    float* __restrict__ as2,
                                                    float* __restrict__ ad2, int n) {
    int tid = threadIdx.x;
    int l = tid & 63, w = tid >> 6;
    int lr = l & 15, lg = l >> 4;
    int row0 = (int)blockIdx.x * 64;
    int arow = row0 + w * 16 + lr;
    size_t abase = (size_t)(arow < n ? arow : 0) * 128;   // clamp: row 0 always valid
    f16x8 af[4];
#pragma unroll
    for (int kk = 0; kk < 4; ++kk)
        af[kk] = *(const f16x8*)&hph[abase + kk * 32 + lg * 8];
    f32x4 acc[2];
    acc[0] = (f32x4)0.f; acc[1] = (f32x4)0.f;
#pragma unroll
    for (int t = 0; t < 2; ++t)
#pragma unroll
        for (int kk = 0; kk < 4; ++kk) {
            f16x8 bf = *(const f16x8*)&W2t[(t * 16 + lr) * 128 + kk * 32 + lg * 8];
            acc[t] = __builtin_amdgcn_mfma_f32_16x16x32_f16(af[kk], bf, acc[t], 0, 0, 0);
        }
    float a0 = a_src[lr], a1 = a_src[16 + lr];
    float d0 = a_dst[lr], d1 = a_dst[16 + lr];
#pragma unroll
    for (int r = 0; r < 4; ++r) {
        int row = row0 + w * 16 + lg * 4 + r;
        float ps = acc[0][r] * a0 + acc[1][r] * a1;
        float pd = acc[0][r] * d0 + acc[1][r] * d1;
#pragma unroll
        for (int o = 1; o < 16; o <<= 1) { ps += __shfl_xor(ps, o); pd += __shfl_xor(pd, o); }
        if (row < n) {
            h2h[(size_t)row * 32 + lr] = (_Float16)acc[0][r];
            h2h[(size_t)row * 32 + 16 + lr] = (_Float16)acc[1][r];
            if (lr == 0) { as2[row] = ps; ad2[row] = pd; }
        }
    }
}

// ---------------- layer-1 softmax + aggregate: wave/node, fp16 gather ----------------

__global__ __launch_bounds__(256) void agg1_kernel(const _Float16* __restrict__ h1h,
                                                   const float4* __restrict__ as1,
                                                   const float4* __restrict__ ad1,
                                                   const int* __restrict__ rp,
                                                   const int* __restrict__ col,
                                                   const float* __restrict__ b1,
                                                   _Float16* __restrict__ hph, int n) {
    __shared__ float4 s_p[4][64];
    int wave = threadIdx.x >> 6, lane = threadIdx.x & 63;
    int nid = blockIdx.x * 4 + wave;
    if (nid >= n) return;
    int start = rp[nid], end = rp[nid + 1];
    float4 adn = ad1[nid], asn = as1[nid];
    float4 psf;
    psf.x = __expf(leaky(asn.x + adn.x));
    psf.y = __expf(leaky(asn.y + adn.y));
    psf.z = __expf(leaky(asn.z + adn.z));
    psf.w = __expf(leaky(asn.w + adn.w));
    float4 dsum = make_float4(0.f, 0.f, 0.f, 0.f);
    int g = lane & 15, sub = lane >> 4;   // g: 8-ch group, sub: edge subset
    int head = g >> 2;                    // channels g*8..g*8+7 lie in head g/4
    float4 a0 = make_float4(0.f, 0.f, 0.f, 0.f);
    float4 a1 = a0;                       // 8 fp32 accs for ch [g*8, g*8+8)

    for (int base = start; base < end; base += 64) {
        int i = base + lane;
        int sidx = 0;
        float4 p = make_float4(0.f, 0.f, 0.f, 0.f);
        if (i < end) {
            sidx = col[i];
            float4 a = as1[sidx];
            p.x = __expf(leaky(a.x + adn.x));
            p.y = __expf(leaky(a.y + adn.y));
            p.z = __expf(leaky(a.z + adn.z));
            p.w = __expf(leaky(a.w + adn.w));
            dsum.x += p.x; dsum.y += p.y; dsum.z += p.z; dsum.w += p.w;
        }
        s_p[wave][lane] = p;              // intra-wave LDS, program order per wave
        int len = min(64, end - base);
        int steps = (len + 3) >> 2;       // wave-uniform; 4 edges per step
        for (int s = 0; s < steps; ++s) {
            int j = s * 4 + sub;
            int js = (j < len) ? j : 0;
            int rj = __shfl(sidx, js);    // all 64 lanes active
            if (j < len) {
                float pj = ((const float*)&s_p[wave][js])[head];
                H8 u = ((const H8*)(h1h + (size_t)rj * 128))[g];
                a0.x += (float)u.h[0].x * pj; a0.y += (float)u.h[0].y * pj;
                a0.z += (float)u.h[1].x * pj; a0.w += (float)u.h[1].y * pj;
                a1.x += (float)u.h[2].x * pj; a1.y += (float)u.h[2].y * pj;
                a1.z += (float)u.h[3].x * pj; a1.w += (float)u.h[3].y * pj;
            }
        }
    }
    // self loop (one edge-subset adds it)
    if (sub == 0) {
        float pj = (head == 0) ? psf.x : (head == 1) ? psf.y : (head == 2) ? psf.z : psf.w;
        H8 u = ((const H8*)(h1h + (size_t)nid * 128))[g];
        a0.x += (float)u.h[0].x * pj; a0.y += (float)u.h[0].y * pj;
        a0.z += (float)u.h[1].x * pj; a0.w += (float)u.h[1].y * pj;
        a1.x += (float)u.h[2].x * pj; a1.y += (float)u.h[2].y * pj;
        a1.z += (float)u.h[3].x * pj; a1.w += (float)u.h[3].y * pj;
    }
    if (lane == 0) {
        dsum.x += psf.x; dsum.y += psf.y; dsum.z += psf.z; dsum.w += psf.w;
    }
#pragma unroll
    for (int o = 1; o < 64; o <<= 1) {
        dsum.x += __shfl_xor(dsum.x, o); dsum.y += __shfl_xor(dsum.y, o);
        dsum.z += __shfl_xor(dsum.z, o); dsum.w += __shfl_xor(dsum.w, o);
    }
#pragma unroll
    for (int o = 16; o < 64; o <<= 1) {   // reduce over 4 edge subsets (same g)
        a0.x += __shfl_xor(a0.x, o); a0.y += __shfl_xor(a0.y, o);
        a0.z += __shfl_xor(a0.z, o); a0.w += __shfl_xor(a0.w, o);
        a1.x += __shfl_xor(a1.x, o); a1.y += __shfl_xor(a1.y, o);
        a1.z += __shfl_xor(a1.z, o); a1.w += __shfl_xor(a1.w, o);
    }
    if (sub == 0) {
        float den = (head == 0) ? dsum.x : (head == 1) ? dsum.y : (head == 2) ? dsum.z : dsum.w;
        float inv = __builtin_amdgcn_rcpf(den);
        const float4* b4 = (const float4*)b1;
        float4 bb0 = b4[g * 2], bb1 = b4[g * 2 + 1];
        float4 r0 = make_float4(elu(a0.x * inv + bb0.x), elu(a0.y * inv + bb0.y),
                                elu(a0.z * inv + bb0.z), elu(a0.w * inv + bb0.w));
        float4 r1 = make_float4(elu(a1.x * inv + bb1.x), elu(a1.y * inv + bb1.y),
                                elu(a1.z * inv + bb1.z), elu(a1.w * inv + bb1.w));
        H8 o8;
        o8.h[0] = half2v{(_Float16)r0.x, (_Float16)r0.y};
        o8.h[1] = half2v{(_Float16)r0.z, (_Float16)r0.w};
        o8.h[2] = half2v{(_Float16)r1.x, (_Float16)r1.y};
        o8.h[3] = half2v{(_Float16)r1.z, (_Float16)r1.w};
        *(float4*)&hph[(size_t)nid * 128 + g * 8] = o8.f4;
    }
}

// ---------------- layer-2 softmax + aggregate: wave/node, fp16 gather ----------------

__global__ __launch_bounds__(256) void agg2_kernel(const _Float16* __restrict__ h2h,
                                                   const float* __restrict__ as2,
                                                   const float* __restrict__ ad2,
                                                   const int* __restrict__ rp,
                                                   const int* __restrict__ col,
                                                   const float* __restrict__ b2,
                                                   float* __restrict__ out, int n) {
    int wave = threadIdx.x >> 6, lane = threadIdx.x & 63;
    int nid = blockIdx.x * 4 + wave;
    if (nid >= n) return;
    int start = rp[nid], end = rp[nid + 1];
    float adn = ad2[nid];
    float psf = __expf(leaky(as2[nid] + adn));
    float dsum = 0.f;
    int g = lane & 7, sub = lane >> 3;
    float4 acc = make_float4(0.f, 0.f, 0.f, 0.f);
    for (int base = start; base < end; base += 64) {
        int i = base + lane;
        int sidx = 0;
        float p = 0.f;
        if (i < end) {
            sidx = col[i];
            p = __expf(leaky(as2[sidx] + adn));
            dsum += p;
        }
        int len = min(64, end - base);
        int steps = (len + 7) >> 3;
        for (int s = 0; s < steps; ++s) {
            int j = s * 8 + sub;
            int js = (j < len) ? j : 0;
            int rj = __shfl(sidx, js);
            float pj = __shfl(p, js);
            if (j < len) {
                H4 u = ((const H4*)(h2h + (size_t)rj * 32))[g];
                acc.x += (float)u.h[0].x * pj; acc.y += (float)u.h[0].y * pj;
                acc.z += (float)u.h[1].x * pj; acc.w += (float)u.h[1].y * pj;
            }
        }
    }
    if (sub == 0) {
        H4 u = ((const H4*)(h2h + (size_t)nid * 32))[g];
        acc.x += (float)u.h[0].x * psf; acc.y += (float)u.h[0].y * psf;
        acc.z += (float)u.h[1].x * psf; acc.w += (float)u.h[1].y * psf;
    }
    if (lane == 0) dsum += psf;
#pragma unroll
    for (int o = 1; o < 64; o <<= 1) dsum += __shfl_xor(dsum, o);
#pragma unroll
    for (int o = 8; o < 64; o <<= 1) {
        acc.x += __shfl_xor(acc.x, o); acc.y += __shfl_xor(acc.y, o);
        acc.z += __shfl_xor(acc.z, o); acc.w += __shfl_xor(acc.w, o);
    }
    if (sub == 0) {
        float inv = __builtin_amdgcn_rcpf(dsum);
        float4 bb = ((const float4*)b2)[g];
        ((float4*)(out + (size_t)nid * 32))[g] =
            make_float4(acc.x * inv + bb.x, acc.y * inv + bb.y,
                        acc.z * inv + bb.z, acc.w * inv + bb.w);
    }
}

// ---------------- launch ----------------

extern "C" void kernel_launch(void* const* d_in, const int* in_sizes, int n_in,
                              void* d_out, int out_size, void* d_ws, size_t ws_size,
                              hipStream_t stream) {
    const float* x      = (const float*)d_in[0];
    const int*   ei     = (const int*)d_in[1];
    const float* W1     = (const float*)d_in[2];
    const float* a_src1 = (const float*)d_in[3];
    const float* a_dst1 = (const float*)d_in[4];
    const float* b1     = (const float*)d_in[5];
    const float* W2     = (const float*)d_in[6];
    const float* a_src2 = (const float*)d_in[7];
    const float* a_dst2 = (const float*)d_in[8];
    const float* b2     = (const float*)d_in[9];
    float* out = (float*)d_out;

    const int N = in_sizes[0] / 128;
    const int E = in_sizes[1] / 2;
    const int* src = ei;
    const int* dstp = ei + E;

    uint8_t* w = (uint8_t*)d_ws;
    auto carve = [&](size_t bytes) {
        uint8_t* p = w;
        w += (bytes + 255) & ~(size_t)255;
        return p;
    };
    _Float16* h1h = (_Float16*)carve((size_t)N * 128 * 2);
    _Float16* hph = (_Float16*)carve((size_t)N * 128 * 2);
    _Float16* h2h = (_Float16*)carve((size_t)N * 32 * 2);
    _Float16* W1t = (_Float16*)carve((size_t)128 * 128 * 2);
    _Float16* W2t = (_Float16*)carve((size_t)32 * 128 * 2);
    float* as1 = (float*)carve((size_t)N * 4 * 4);
    float* ad1 = (float*)carve((size_t)N * 4 * 4);
    float* as2 = (float*)carve((size_t)N * 4);
    float* ad2 = (float*)carve((size_t)N * 4);
    int* rp    = (int*)carve((size_t)(N + 1) * 4);
    int* cnt   = (int*)carve((size_t)N * 4);
    int* col   = (int*)carve((size_t)E * 4);
    int* ranks = (int*)carve((size_t)E * 4);
    int* bsum  = (int*)carve(64 * 4);

    const int gemmBlocks = (N + 63) / 64;
    const int countBlocks = (E + 255) / 256;
    const int G = (N + 1023) / 1024;   // <= 64 for N <= 65536
    const int prepN = (N > 128 * 128) ? N : 128 * 128;

    // D1: zero counts + fp16 weight transposes (replaces memset dispatch)
    prep_kernel<<<(prepN + 255) / 256, 256, 0, stream>>>(W1, W2, W1t, W2t, cnt, N);
    // D2: MFMA gemm1 + count (count atomics hide under gemm)
    gemm1_count_kernel<<<gemmBlocks + countBlocks, 256, 0, stream>>>(
        x, W1t, a_src1, a_dst1, h1h, as1, ad1, N, gemmBlocks, dstp, cnt, ranks, E);
    // D3/D4: parallel scan cnt -> rp
    scanA_kernel<<<G, 256, 0, stream>>>(cnt, bsum, N);
    scanC_kernel<<<G, 256, 0, stream>>>(cnt, bsum, rp, N, G);
    // D5: atomic-free scatter via ranks
    scatter_kernel<<<(E + 255) / 256, 256, 0, stream>>>(src, dstp, rp, ranks, col, E);
    // D6: layer-1 aggregate
    agg1_kernel<<<(N + 3) / 4, 256, 0, stream>>>(h1h, (const float4*)as1, (const float4*)ad1,
                                                 rp, col, b1, hph, N);
    // D7: layer-2 GEMM (MFMA, no LDS)
    gemm2_kernel<<<(N + 63) / 64, 256, 0, stream>>>(hph, W2t, a_src2, a_dst2, h2h, as2, ad2, N);
    // D8: layer-2 aggregate
    agg2_kernel<<<(N + 3) / 4, 256, 0, stream>>>(h2h, as2, ad2, rp, col, b2, out, N);
}